// Round 1
// baseline (410.529 us; speedup 1.0000x reference)
//
#include <hip/hip_runtime.h>
#include <hip/hip_bf16.h>

#define T_SEQ   2048
#define HIDDEN  2880
#define NQ      64
#define NKV     8
#define HD      64
#define QSIZE   4096   // NQ*HD
#define KVSIZE  512    // NKV*HD
#define QKV_N   5120   // QSIZE + 2*KVSIZE
#define WINDOW  128
#define SCALE_F 0.125f // HD^-0.5
#define N2PAD   2944   // HIDDEN padded to 128 multiple

typedef unsigned short u16;
typedef __attribute__((ext_vector_type(8))) short short8;
typedef __attribute__((ext_vector_type(4))) float f32x4;

__device__ __forceinline__ u16 f2bf(float f) {
  __hip_bfloat16 b = __float2bfloat16(f);
  u16 u; __builtin_memcpy(&u, &b, 2); return u;
}
__device__ __forceinline__ float bf2f(u16 u) {
  __hip_bfloat16 b; __builtin_memcpy(&b, &u, 2); return __bfloat162float(b);
}

__device__ __forceinline__ void gload16(const u16* g, u16* l) {
  __builtin_amdgcn_global_load_lds(
      (const __attribute__((address_space(1))) void*)g,
      (__attribute__((address_space(3))) void*)l, 16, 0, 0);
}

// ---------------- cast f32 -> bf16 (vectorized) ----------------
__global__ void cast_f32_bf16_kernel(const float* __restrict__ in,
                                     u16* __restrict__ out, int n4) {
  int i = blockIdx.x * blockDim.x + threadIdx.x;
  if (i < n4) {
    float4 v = ((const float4*)in)[i];
    ushort4 o;
    o.x = f2bf(v.x); o.y = f2bf(v.y); o.z = f2bf(v.z); o.w = f2bf(v.w);
    ((ushort4*)out)[i] = o;
  }
}

// ---------------- transpose + cast: in[R][C] f32 -> out[C][R] bf16 ----------------
__global__ void transpose_cast_kernel(const float* __restrict__ in,
                                      u16* __restrict__ out, int R, int C) {
  __shared__ float tile[32][33];
  int tx = threadIdx.x & 31, ty = threadIdx.x >> 5; // 32 x 8
  int r0 = blockIdx.y * 32, c0 = blockIdx.x * 32;
#pragma unroll
  for (int i = 0; i < 32; i += 8)
    tile[ty + i][tx] = in[(size_t)(r0 + ty + i) * C + c0 + tx];
  __syncthreads();
#pragma unroll
  for (int i = 0; i < 32; i += 8)
    out[(size_t)(c0 + ty + i) * R + r0 + tx] = f2bf(tile[tx][ty + i]);
}

// ---------------- bf16 MFMA GEMM: C[M][N] = A[M][K] * B^T  (B is [N][K]) ----------------
// 128x128 tile, BK=32, 256 threads (4 waves, 2x2 of 64x64), m97 structure.
template <int OUT_BF16>
__global__ __launch_bounds__(256)
void gemm_bt_kernel(const u16* __restrict__ A, const u16* __restrict__ B,
                    void* __restrict__ Cout, int K, int Bvalid, int Nout, int ldc) {
  __shared__ __align__(16) u16 As[128 * 32];
  __shared__ __align__(16) u16 Bs[128 * 32];
  const int tid = threadIdx.x;
  const int lane = tid & 63, wave = tid >> 6;
  const int quad = lane >> 4, l16 = lane & 15;
  const int wm = wave >> 1, wn = wave & 1;
  const int m0 = blockIdx.y * 128, n0 = blockIdx.x * 128;

  const int i0 = tid, i1 = tid + 256;
  const int ar0 = i0 >> 2, ac0 = (i0 & 3) * 8;
  const int ar1 = i1 >> 2, ac1 = (i1 & 3) * 8;
  const int br0 = (n0 + ar0 < Bvalid) ? (n0 + ar0) : (Bvalid - 1);
  const int br1 = (n0 + ar1 < Bvalid) ? (n0 + ar1) : (Bvalid - 1);
  const u16* Ag0 = A + (size_t)(m0 + ar0) * K + ac0;
  const u16* Ag1 = A + (size_t)(m0 + ar1) * K + ac1;
  const u16* Bg0 = B + (size_t)br0 * K + ac0;
  const u16* Bg1 = B + (size_t)br1 * K + ac1;
  u16* Al0 = As + i0 * 8;
  u16* Al1 = As + i1 * 8;
  u16* Bl0 = Bs + i0 * 8;
  u16* Bl1 = Bs + i1 * 8;

  f32x4 acc[4][4] = {};

  for (int kt = 0; kt < K; kt += 32) {
    gload16(Ag0 + kt, Al0);
    gload16(Ag1 + kt, Al1);
    gload16(Bg0 + kt, Bl0);
    gload16(Bg1 + kt, Bl1);
    asm volatile("s_waitcnt vmcnt(0)" ::: "memory");
    __syncthreads();
    short8 af[4], bf[4];
#pragma unroll
    for (int i = 0; i < 4; ++i)
      af[i] = *(const short8*)(As + (wm * 64 + i * 16 + l16) * 32 + quad * 8);
#pragma unroll
    for (int j = 0; j < 4; ++j)
      bf[j] = *(const short8*)(Bs + (wn * 64 + j * 16 + l16) * 32 + quad * 8);
#pragma unroll
    for (int i = 0; i < 4; ++i)
#pragma unroll
      for (int j = 0; j < 4; ++j)
        acc[i][j] = __builtin_amdgcn_mfma_f32_16x16x32_bf16(af[i], bf[j], acc[i][j], 0, 0, 0);
    __syncthreads();
  }

#pragma unroll
  for (int i = 0; i < 4; ++i) {
    const int row = m0 + wm * 64 + i * 16 + quad * 4;
#pragma unroll
    for (int j = 0; j < 4; ++j) {
      const int col = n0 + wn * 64 + j * 16 + l16;
      if (col < Nout) {
#pragma unroll
        for (int r = 0; r < 4; ++r) {
          if (OUT_BF16)
            ((u16*)Cout)[(size_t)(row + r) * ldc + col] = f2bf(acc[i][j][r]);
          else
            ((float*)Cout)[(size_t)(row + r) * ldc + col] = acc[i][j][r];
        }
      }
    }
  }
}

// ---------------- RoPE (neox) on q and k, bf16 in/out ----------------
__global__ void rope_kernel(const u16* __restrict__ qkv,
                            const int* __restrict__ positions,
                            u16* __restrict__ qb, u16* __restrict__ kb) {
  const int t = blockIdx.x;
  const float pos = (float)positions[t];
  const u16* row = qkv + (size_t)t * QKV_N;
  for (int p = threadIdx.x; p < (NQ + NKV) * 32; p += 256) {
    const int head = p >> 5;
    const int i = p & 31;
    // inv_freq = theta^(-i/32) ; log2(150000)/32 = 0.53733134...
    const float inv = exp2f(-(float)i * 0.53733134f);
    float s, c;
    sincosf(pos * inv, &s, &c);
    float x1, x2; u16* dst;
    if (head < NQ) {
      x1 = bf2f(row[head * HD + i]);
      x2 = bf2f(row[head * HD + i + 32]);
      dst = qb + (size_t)t * QSIZE + head * HD;
    } else {
      int kh = head - NQ;
      x1 = bf2f(row[QSIZE + kh * HD + i]);
      x2 = bf2f(row[QSIZE + kh * HD + i + 32]);
      dst = kb + (size_t)t * KVSIZE + kh * HD;
    }
    dst[i]      = f2bf(x1 * c - x2 * s);
    dst[i + 32] = f2bf(x2 * c + x1 * s);
  }
}

// ---------------- windowed attention with sinks ----------------
// block = (q-tile of 64, head). Keys [q0-128, q0+64) = 192. 4 waves, each a
// 16-query strip. QK via MFMA -> register softmax (mask+sink) -> P via LDS
// (C-layout -> A-layout) -> PV via MFMA with V^T staged in LDS.
__global__ __launch_bounds__(256)
void attn_kernel(const u16* __restrict__ qb, const u16* __restrict__ kb,
                 const u16* __restrict__ qkvb, const float* __restrict__ sinks,
                 u16* __restrict__ attnb) {
  __shared__ __align__(16) u16 Qs[64 * 72];
  __shared__ __align__(16) u16 KP[192 * 72];   // K tile; reused for P[64][200]
  __shared__ __align__(16) u16 Vt[64 * 200];   // V^T [dim][key]
  const int qt = blockIdx.x, h = blockIdx.y, g = h >> 3;
  const int q0 = qt * 64, kstart = q0 - 128;
  const int tid = threadIdx.x;
  const int lane = tid & 63, wave = tid >> 6;
  const int quad = lane >> 4, l16 = lane & 15;

  for (int s = tid; s < 512; s += 256) {          // Q: 64x64
    int r = s >> 3, c8 = (s & 7) * 8;
    *(short8*)(Qs + r * 72 + c8) =
        *(const short8*)(qb + (size_t)(q0 + r) * QSIZE + h * HD + c8);
  }
  for (int s = tid; s < 1536; s += 256) {         // K: 192x64
    int r = s >> 3, c8 = (s & 7) * 8;
    int tg = kstart + r; tg = tg < 0 ? 0 : tg;
    *(short8*)(KP + r * 72 + c8) =
        *(const short8*)(kb + (size_t)tg * KVSIZE + g * HD + c8);
  }
  for (int s = tid; s < 1536; s += 256) {         // V^T: read [key][dim], scatter
    int tl = s >> 3, c8 = (s & 7) * 8;
    int tg = kstart + tl; tg = tg < 0 ? 0 : tg;
    short8 v = *(const short8*)(qkvb + (size_t)tg * QKV_N + QSIZE + KVSIZE + g * HD + c8);
#pragma unroll
    for (int j = 0; j < 8; ++j) Vt[(c8 + j) * 200 + tl] = (u16)v[j];
  }
  __syncthreads();

  short8 aq[2];
#pragma unroll
  for (int kk = 0; kk < 2; ++kk)
    aq[kk] = *(const short8*)(Qs + (wave * 16 + l16) * 72 + kk * 32 + quad * 8);
  f32x4 sc[12];
#pragma unroll
  for (int jf = 0; jf < 12; ++jf) {
    f32x4 c = {0.f, 0.f, 0.f, 0.f};
#pragma unroll
    for (int kk = 0; kk < 2; ++kk) {
      short8 bk = *(const short8*)(KP + (jf * 16 + l16) * 72 + kk * 32 + quad * 8);
      c = __builtin_amdgcn_mfma_f32_16x16x32_bf16(aq[kk], bk, c, 0, 0, 0);
    }
    sc[jf] = c;
  }

  const float sink = sinks[h];
  float pinv[4];
#pragma unroll
  for (int r = 0; r < 4; ++r) {
    const int qg = q0 + wave * 16 + quad * 4 + r;
    float mx = -3.0e38f;
#pragma unroll
    for (int jf = 0; jf < 12; ++jf) {
      int kg = kstart + jf * 16 + l16;
      bool valid = (kg >= 0) && (kg <= qg) && (qg - kg < WINDOW);
      float sv = valid ? sc[jf][r] * SCALE_F : -3.0e38f;
      sc[jf][r] = sv;
      mx = fmaxf(mx, sv);
    }
#pragma unroll
    for (int d = 1; d < 16; d <<= 1) mx = fmaxf(mx, __shfl_xor(mx, d, 64));
    mx = fmaxf(mx, sink);
    float sum = 0.f;
#pragma unroll
    for (int jf = 0; jf < 12; ++jf) {
      float e = __expf(sc[jf][r] - mx);
      sc[jf][r] = e;
      sum += e;
    }
#pragma unroll
    for (int d = 1; d < 16; d <<= 1) sum += __shfl_xor(sum, d, 64);
    sum += __expf(sink - mx);
    pinv[r] = 1.0f / sum;
  }

  __syncthreads();   // everyone done reading K tile before P overwrites it
#pragma unroll
  for (int jf = 0; jf < 12; ++jf)
#pragma unroll
    for (int r = 0; r < 4; ++r)
      KP[(wave * 16 + quad * 4 + r) * 200 + jf * 16 + l16] = f2bf(sc[jf][r] * pinv[r]);
  __syncthreads();

  f32x4 o[4] = {};
#pragma unroll
  for (int kk = 0; kk < 6; ++kk) {
    short8 ap = *(const short8*)(KP + (wave * 16 + l16) * 200 + kk * 32 + quad * 8);
#pragma unroll
    for (int jf = 0; jf < 4; ++jf) {
      short8 bv = *(const short8*)(Vt + (jf * 16 + l16) * 200 + kk * 32 + quad * 8);
      o[jf] = __builtin_amdgcn_mfma_f32_16x16x32_bf16(ap, bv, o[jf], 0, 0, 0);
    }
  }
#pragma unroll
  for (int jf = 0; jf < 4; ++jf)
#pragma unroll
    for (int r = 0; r < 4; ++r) {
      int qg = q0 + wave * 16 + quad * 4 + r;
      attnb[(size_t)qg * QSIZE + h * HD + jf * 16 + l16] = f2bf(o[jf][r]);
    }
}

extern "C" void kernel_launch(void* const* d_in, const int* in_sizes, int n_in,
                              void* d_out, int out_size, void* d_ws, size_t ws_size,
                              hipStream_t stream) {
  (void)in_sizes; (void)n_in; (void)out_size; (void)ws_size;
  const int*   positions = (const int*)d_in[0];
  const float* hidden    = (const float*)d_in[1];
  const float* w_qkv     = (const float*)d_in[2];
  const float* w_o       = (const float*)d_in[3];
  const float* sinks     = (const float*)d_in[4];

  char* p = (char*)d_ws;
  u16* Xb    = (u16*)p; p += (size_t)T_SEQ * HIDDEN * 2;   // hidden bf16
  u16* Wqt   = (u16*)p; p += (size_t)QKV_N * HIDDEN * 2;   // w_qkv^T bf16 [5120][2880]
  u16* Wot   = (u16*)p; p += (size_t)HIDDEN * QSIZE * 2;   // w_o^T bf16 [2880][4096]
  u16* qkvb  = (u16*)p; p += (size_t)T_SEQ * QKV_N * 2;    // qkv bf16
  u16* qb    = (u16*)p; p += (size_t)T_SEQ * QSIZE * 2;    // roped q bf16
  u16* kb    = (u16*)p; p += (size_t)T_SEQ * KVSIZE * 2;   // roped k bf16
  u16* attnb = (u16*)p; p += (size_t)T_SEQ * QSIZE * 2;    // attention out bf16

  cast_f32_bf16_kernel<<<(T_SEQ * HIDDEN / 4 + 255) / 256, 256, 0, stream>>>(
      hidden, Xb, T_SEQ * HIDDEN / 4);
  transpose_cast_kernel<<<dim3(QKV_N / 32, HIDDEN / 32), 256, 0, stream>>>(
      w_qkv, Wqt, HIDDEN, QKV_N);
  transpose_cast_kernel<<<dim3(HIDDEN / 32, QSIZE / 32), 256, 0, stream>>>(
      w_o, Wot, QSIZE, HIDDEN);
  gemm_bt_kernel<1><<<dim3(QKV_N / 128, T_SEQ / 128), 256, 0, stream>>>(
      Xb, Wqt, (void*)qkvb, HIDDEN, QKV_N, QKV_N, QKV_N);
  rope_kernel<<<T_SEQ, 256, 0, stream>>>(qkvb, positions, qb, kb);
  attn_kernel<<<dim3(T_SEQ / 64, NQ), 256, 0, stream>>>(qb, kb, qkvb, sinks, attnb);
  gemm_bt_kernel<0><<<dim3(N2PAD / 128, T_SEQ / 128), 256, 0, stream>>>(
      attnb, Wot, d_out, QSIZE, HIDDEN, HIDDEN, HIDDEN);
}

// Round 2
// 397.377 us; speedup vs baseline: 1.0331x; 1.0331x over previous
//
#include <hip/hip_runtime.h>
#include <hip/hip_bf16.h>

#define T_SEQ   2048
#define HIDDEN  2880
#define NQ      64
#define NKV     8
#define HD      64
#define QSIZE   4096   // NQ*HD
#define KVSIZE  512    // NKV*HD
#define QKV_N   5120   // QSIZE + 2*KVSIZE
#define WINDOW  128
#define SCALE_F 0.125f // HD^-0.5
#define N2PAD   2944   // HIDDEN padded to 128 multiple

typedef unsigned short u16;
typedef __attribute__((ext_vector_type(8))) short short8;
typedef __attribute__((ext_vector_type(4))) float f32x4;

__device__ __forceinline__ u16 f2bf(float f) {
  __hip_bfloat16 b = __float2bfloat16(f);
  u16 u; __builtin_memcpy(&u, &b, 2); return u;
}
__device__ __forceinline__ float bf2f(u16 u) {
  __hip_bfloat16 b; __builtin_memcpy(&b, &u, 2); return __bfloat162float(b);
}

__device__ __forceinline__ void gload16(const u16* g, u16* l) {
  __builtin_amdgcn_global_load_lds(
      (const __attribute__((address_space(1))) void*)g,
      (__attribute__((address_space(3))) void*)l, 16, 0, 0);
}

// ---------------- cast f32 -> bf16 (vectorized) ----------------
__global__ void cast_f32_bf16_kernel(const float* __restrict__ in,
                                     u16* __restrict__ out, int n4) {
  int i = blockIdx.x * blockDim.x + threadIdx.x;
  if (i < n4) {
    float4 v = ((const float4*)in)[i];
    ushort4 o;
    o.x = f2bf(v.x); o.y = f2bf(v.y); o.z = f2bf(v.z); o.w = f2bf(v.w);
    ((ushort4*)out)[i] = o;
  }
}

// ---------------- transpose + cast: in[R][C] f32 -> out[C][R] bf16 ----------------
// 64 rows x 32 cols of input per block; output writes are 128B/wave coalesced.
__global__ void transpose_cast_kernel(const float* __restrict__ in,
                                      u16* __restrict__ out, int R, int C) {
  __shared__ float tile[32][65];  // [col][row]
  const int r0 = blockIdx.y * 64, c0 = blockIdx.x * 32;
  const int tx = threadIdx.x & 31, ty = threadIdx.x >> 5;  // 32 x 8
#pragma unroll
  for (int i = 0; i < 64; i += 8)
    tile[tx][ty + i] = in[(size_t)(r0 + ty + i) * C + c0 + tx];
  __syncthreads();
  const int tx2 = threadIdx.x & 63, ty2 = threadIdx.x >> 6;  // 64 x 4
#pragma unroll
  for (int i = 0; i < 32; i += 4)
    out[(size_t)(c0 + ty2 + i) * R + r0 + tx2] = f2bf(tile[ty2 + i][tx2]);
}

// ---------------- bf16 MFMA GEMM: C[M][N] = A[M][K] * B^T  (B is [N][K]) ----------------
// 128x128 tile, BK=32, 256 threads (4 waves, 2x2 of 64x64), m97 structure.
// M-tiles on blockIdx.x so co-resident blocks share B n-tiles (L2/LLC locality).
template <int OUT_BF16>
__global__ __launch_bounds__(256)
void gemm_bt_kernel(const u16* __restrict__ A, const u16* __restrict__ B,
                    void* __restrict__ Cout, int K, int Bvalid, int Nout, int ldc) {
  __shared__ __align__(16) u16 As[128 * 32];
  __shared__ __align__(16) u16 Bs[128 * 32];
  const int tid = threadIdx.x;
  const int lane = tid & 63, wave = tid >> 6;
  const int quad = lane >> 4, l16 = lane & 15;
  const int wm = wave >> 1, wn = wave & 1;
  const int m0 = blockIdx.x * 128, n0 = blockIdx.y * 128;

  const int i0 = tid, i1 = tid + 256;
  const int ar0 = i0 >> 2, ac0 = (i0 & 3) * 8;
  const int ar1 = i1 >> 2, ac1 = (i1 & 3) * 8;
  const int br0 = (n0 + ar0 < Bvalid) ? (n0 + ar0) : (Bvalid - 1);
  const int br1 = (n0 + ar1 < Bvalid) ? (n0 + ar1) : (Bvalid - 1);
  const u16* Ag0 = A + (size_t)(m0 + ar0) * K + ac0;
  const u16* Ag1 = A + (size_t)(m0 + ar1) * K + ac1;
  const u16* Bg0 = B + (size_t)br0 * K + ac0;
  const u16* Bg1 = B + (size_t)br1 * K + ac1;
  u16* Al0 = As + i0 * 8;
  u16* Al1 = As + i1 * 8;
  u16* Bl0 = Bs + i0 * 8;
  u16* Bl1 = Bs + i1 * 8;

  f32x4 acc[4][4] = {};

  for (int kt = 0; kt < K; kt += 32) {
    gload16(Ag0 + kt, Al0);
    gload16(Ag1 + kt, Al1);
    gload16(Bg0 + kt, Bl0);
    gload16(Bg1 + kt, Bl1);
    asm volatile("s_waitcnt vmcnt(0)" ::: "memory");
    __syncthreads();
    short8 af[4], bf[4];
#pragma unroll
    for (int i = 0; i < 4; ++i)
      af[i] = *(const short8*)(As + (wm * 64 + i * 16 + l16) * 32 + quad * 8);
#pragma unroll
    for (int j = 0; j < 4; ++j)
      bf[j] = *(const short8*)(Bs + (wn * 64 + j * 16 + l16) * 32 + quad * 8);
#pragma unroll
    for (int i = 0; i < 4; ++i)
#pragma unroll
      for (int j = 0; j < 4; ++j)
        acc[i][j] = __builtin_amdgcn_mfma_f32_16x16x32_bf16(af[i], bf[j], acc[i][j], 0, 0, 0);
    __syncthreads();
  }

#pragma unroll
  for (int i = 0; i < 4; ++i) {
    const int row = m0 + wm * 64 + i * 16 + quad * 4;
#pragma unroll
    for (int j = 0; j < 4; ++j) {
      const int col = n0 + wn * 64 + j * 16 + l16;
      if (col < Nout) {
#pragma unroll
        for (int r = 0; r < 4; ++r) {
          if (OUT_BF16)
            ((u16*)Cout)[(size_t)(row + r) * ldc + col] = f2bf(acc[i][j][r]);
          else
            ((float*)Cout)[(size_t)(row + r) * ldc + col] = acc[i][j][r];
        }
      }
    }
  }
}

// ---------------- RoPE (neox) on q and k, bf16 in/out ----------------
__global__ void rope_kernel(const u16* __restrict__ qkv,
                            const int* __restrict__ positions,
                            u16* __restrict__ qb, u16* __restrict__ kb) {
  const int t = blockIdx.x;
  const float pos = (float)positions[t];
  const u16* row = qkv + (size_t)t * QKV_N;
  for (int p = threadIdx.x; p < (NQ + NKV) * 32; p += 256) {
    const int head = p >> 5;
    const int i = p & 31;
    const float inv = exp2f(-(float)i * 0.53733134f);  // theta^(-i/32)
    float s, c;
    sincosf(pos * inv, &s, &c);
    float x1, x2; u16* dst;
    if (head < NQ) {
      x1 = bf2f(row[head * HD + i]);
      x2 = bf2f(row[head * HD + i + 32]);
      dst = qb + (size_t)t * QSIZE + head * HD;
    } else {
      int kh = head - NQ;
      x1 = bf2f(row[QSIZE + kh * HD + i]);
      x2 = bf2f(row[QSIZE + kh * HD + i + 32]);
      dst = kb + (size_t)t * KVSIZE + kh * HD;
    }
    dst[i]      = f2bf(x1 * c - x2 * s);
    dst[i + 32] = f2bf(x2 * c + x1 * s);
  }
}

// ---------------- windowed attention with sinks ----------------
// block = (q-tile of 64, KV GROUP). Grid 32x8 = 256 blocks (1/CU). K/V staged
// ONCE per block; loop over the group's 8 heads. K fragments live in registers
// so the K LDS region is reused for P. V staged raw via global_load_lds then
// LDS-transposed (conflict-free), replacing the old 16-way-conflict scatter.
__global__ __launch_bounds__(256)
void attn_kernel(const u16* __restrict__ qb, const u16* __restrict__ kb,
                 const u16* __restrict__ qkvb, const float* __restrict__ sinks,
                 u16* __restrict__ attnb) {
  __shared__ __align__(16) u16 Qs[64 * 72];     //  9.2 KB
  __shared__ __align__(16) u16 KP[192 * 72];    // 27.6 KB: K tile, then Vraw, then P[64][200]
  __shared__ __align__(16) u16 Vt[64 * 200];    // 25.6 KB: V^T [dim][key]
  const int qt = blockIdx.x, g = blockIdx.y;
  const int q0 = qt * 64, kstart = q0 - 128;
  const int tid = threadIdx.x;
  const int lane = tid & 63, wave = tid >> 6;
  const int quad = lane >> 4, l16 = lane & 15;

  // ---- stage K: 192x64 -> KP stride 72 ----
  for (int s = tid; s < 1536; s += 256) {
    int r = s >> 3, c8 = (s & 7) * 8;
    int tg = kstart + r; tg = tg < 0 ? 0 : tg;
    *(short8*)(KP + r * 72 + c8) =
        *(const short8*)(kb + (size_t)tg * KVSIZE + g * HD + c8);
  }
  __syncthreads();

  // ---- K fragments -> registers (frees KP region) ----
  short8 bk[12][2];
#pragma unroll
  for (int jf = 0; jf < 12; ++jf)
#pragma unroll
    for (int kk = 0; kk < 2; ++kk)
      bk[jf][kk] = *(const short8*)(KP + (jf * 16 + l16) * 72 + kk * 32 + quad * 8);
  __syncthreads();

  // ---- stage V raw 192x64 (stride 64, contiguous) into KP via global_load_lds ----
  {
    const u16* vbase = qkvb + QSIZE + KVSIZE + g * HD;
    for (int it = 0; it < 6; ++it) {
      int s = it * 256 + tid;           // chunk of 8 u16
      int r = s >> 3, c8 = (s & 7) * 8;
      int tg = kstart + r; tg = tg < 0 ? 0 : tg;
      gload16(vbase + (size_t)tg * QKV_N + c8, KP + s * 8);
    }
    asm volatile("s_waitcnt vmcnt(0)" ::: "memory");
    __syncthreads();
  }
  // ---- transpose Vraw[key][dim] -> Vt[dim][key] stride 200 ----
  for (int s = tid; s < 1536; s += 256) {
    int d = s & 63, k8 = s >> 6;        // dim, key-octet
    short8 tmp;
#pragma unroll
    for (int j = 0; j < 8; ++j) tmp[j] = (short)KP[(k8 * 8 + j) * 64 + d];
    *(short8*)(Vt + d * 200 + k8 * 8) = tmp;
  }
  __syncthreads();

  // ---- head loop ----
  for (int h8 = 0; h8 < 8; ++h8) {
    const int h = g * 8 + h8;
    // stage Q for this head: 64x64 -> Qs stride 72
    for (int s = tid; s < 512; s += 256) {
      int r = s >> 3, c8 = (s & 7) * 8;
      *(short8*)(Qs + r * 72 + c8) =
          *(const short8*)(qb + (size_t)(q0 + r) * QSIZE + h * HD + c8);
    }
    __syncthreads();

    short8 aq[2];
#pragma unroll
    for (int kk = 0; kk < 2; ++kk)
      aq[kk] = *(const short8*)(Qs + (wave * 16 + l16) * 72 + kk * 32 + quad * 8);
    f32x4 sc[12];
#pragma unroll
    for (int jf = 0; jf < 12; ++jf) {
      f32x4 c = {0.f, 0.f, 0.f, 0.f};
#pragma unroll
      for (int kk = 0; kk < 2; ++kk)
        c = __builtin_amdgcn_mfma_f32_16x16x32_bf16(aq[kk], bk[jf][kk], c, 0, 0, 0);
      sc[jf] = c;
    }

    const float sink = sinks[h];
    float pinv[4];
#pragma unroll
    for (int r = 0; r < 4; ++r) {
      const int qg = q0 + wave * 16 + quad * 4 + r;
      float mx = -3.0e38f;
#pragma unroll
      for (int jf = 0; jf < 12; ++jf) {
        int kg = kstart + jf * 16 + l16;
        bool valid = (kg >= 0) && (kg <= qg) && (qg - kg < WINDOW);
        float sv = valid ? sc[jf][r] * SCALE_F : -3.0e38f;
        sc[jf][r] = sv;
        mx = fmaxf(mx, sv);
      }
#pragma unroll
      for (int d = 1; d < 16; d <<= 1) mx = fmaxf(mx, __shfl_xor(mx, d, 64));
      mx = fmaxf(mx, sink);
      float sum = 0.f;
#pragma unroll
      for (int jf = 0; jf < 12; ++jf) {
        float e = __expf(sc[jf][r] - mx);
        sc[jf][r] = e;
        sum += e;
      }
#pragma unroll
      for (int d = 1; d < 16; d <<= 1) sum += __shfl_xor(sum, d, 64);
      sum += __expf(sink - mx);
      pinv[r] = 1.0f / sum;
    }

    // write P (own wave's 16 rows) into KP, stride 200
#pragma unroll
    for (int jf = 0; jf < 12; ++jf)
#pragma unroll
      for (int r = 0; r < 4; ++r)
        KP[(wave * 16 + quad * 4 + r) * 200 + jf * 16 + l16] = f2bf(sc[jf][r] * pinv[r]);
    // PV: each wave reads only its OWN 16 P-rows -> no barrier needed here
    f32x4 o[4] = {};
#pragma unroll
    for (int kk = 0; kk < 6; ++kk) {
      short8 ap = *(const short8*)(KP + (wave * 16 + l16) * 200 + kk * 32 + quad * 8);
#pragma unroll
      for (int jf = 0; jf < 4; ++jf)
        o[jf] = __builtin_amdgcn_mfma_f32_16x16x32_bf16(ap, Vt ? *(const short8*)(Vt + (jf * 16 + l16) * 200 + kk * 32 + quad * 8) : ap, o[jf], 0, 0, 0);
    }
#pragma unroll
    for (int jf = 0; jf < 4; ++jf)
#pragma unroll
      for (int r = 0; r < 4; ++r) {
        int qg = q0 + wave * 16 + quad * 4 + r;
        attnb[(size_t)qg * QSIZE + h * HD + jf * 16 + l16] = f2bf(o[jf][r]);
      }
    __syncthreads();  // all waves fully done before Qs/P are overwritten
  }
}

extern "C" void kernel_launch(void* const* d_in, const int* in_sizes, int n_in,
                              void* d_out, int out_size, void* d_ws, size_t ws_size,
                              hipStream_t stream) {
  (void)in_sizes; (void)n_in; (void)out_size; (void)ws_size;
  const int*   positions = (const int*)d_in[0];
  const float* hidden    = (const float*)d_in[1];
  const float* w_qkv     = (const float*)d_in[2];
  const float* w_o       = (const float*)d_in[3];
  const float* sinks     = (const float*)d_in[4];

  char* p = (char*)d_ws;
  u16* Xb    = (u16*)p; p += (size_t)T_SEQ * HIDDEN * 2;   // hidden bf16
  u16* Wqt   = (u16*)p; p += (size_t)QKV_N * HIDDEN * 2;   // w_qkv^T bf16 [5120][2880]
  u16* Wot   = (u16*)p; p += (size_t)HIDDEN * QSIZE * 2;   // w_o^T bf16 [2880][4096]
  u16* qkvb  = (u16*)p; p += (size_t)T_SEQ * QKV_N * 2;    // qkv bf16
  u16* qb    = (u16*)p; p += (size_t)T_SEQ * QSIZE * 2;    // roped q bf16
  u16* kb    = (u16*)p; p += (size_t)T_SEQ * KVSIZE * 2;   // roped k bf16
  u16* attnb = (u16*)p; p += (size_t)T_SEQ * QSIZE * 2;    // attention out bf16

  cast_f32_bf16_kernel<<<(T_SEQ * HIDDEN / 4 + 255) / 256, 256, 0, stream>>>(
      hidden, Xb, T_SEQ * HIDDEN / 4);
  transpose_cast_kernel<<<dim3(QKV_N / 32, HIDDEN / 64), 256, 0, stream>>>(
      w_qkv, Wqt, HIDDEN, QKV_N);
  transpose_cast_kernel<<<dim3(HIDDEN / 32, QSIZE / 64), 256, 0, stream>>>(
      w_o, Wot, QSIZE, HIDDEN);
  gemm_bt_kernel<1><<<dim3(T_SEQ / 128, QKV_N / 128), 256, 0, stream>>>(
      Xb, Wqt, (void*)qkvb, HIDDEN, QKV_N, QKV_N, QKV_N);
  rope_kernel<<<T_SEQ, 256, 0, stream>>>(qkvb, positions, qb, kb);
  attn_kernel<<<dim3(T_SEQ / 64, NKV), 256, 0, stream>>>(qb, kb, qkvb, sinks, attnb);
  gemm_bt_kernel<0><<<dim3(T_SEQ / 128, N2PAD / 128), 256, 0, stream>>>(
      attnb, Wot, d_out, QSIZE, HIDDEN, HIDDEN, HIDDEN);
}

// Round 3
// 343.042 us; speedup vs baseline: 1.1967x; 1.1584x over previous
//
#include <hip/hip_runtime.h>
#include <hip/hip_bf16.h>

#define T_SEQ   2048
#define HIDDEN  2880
#define NQ      64
#define NKV     8
#define HD      64
#define QSIZE   4096   // NQ*HD
#define KVSIZE  512    // NKV*HD
#define QKV_N   5120   // QSIZE + 2*KVSIZE
#define WINDOW  128
#define SCALE_F 0.125f // HD^-0.5
// log2(150000)/32
#define ROPE_L2 0.53733241958f

typedef unsigned short u16;
typedef __attribute__((ext_vector_type(8))) short short8;
typedef __attribute__((ext_vector_type(4))) float f32x4;

__device__ __forceinline__ u16 f2bf(float f) {
  __hip_bfloat16 b = __float2bfloat16(f);
  u16 u; __builtin_memcpy(&u, &b, 2); return u;
}

__device__ __forceinline__ void gload16(const u16* g, u16* l) {
  __builtin_amdgcn_global_load_lds(
      (const __attribute__((address_space(1))) void*)g,
      (__attribute__((address_space(3))) void*)l, 16, 0, 0);
}

// ---------------- prep: cast X + transpose w_qkv + transpose w_o ----------------
#define CAST_BLKS 5760            // 2048*2880/4/256
#define TQ_BX 160
#define TQ_BLKS (160 * 45)        // w_qkv: C=5120/32, R=2880/64
#define TO_BX 90
#define TO_BLKS (90 * 64)         // w_o:  C=2880/32, R=4096/64
#define PREP_BLKS (CAST_BLKS + TQ_BLKS + TO_BLKS)

__global__ void prep_kernel(const float* __restrict__ hidden,
                            const float* __restrict__ w_qkv,
                            const float* __restrict__ w_o,
                            u16* __restrict__ Xb, u16* __restrict__ Wqt,
                            u16* __restrict__ Wot) {
  __shared__ float tile[32][65];
  const int b = blockIdx.x, tid = threadIdx.x;
  if (b < CAST_BLKS) {
    int i = b * 256 + tid;
    float4 v = ((const float4*)hidden)[i];
    ushort4 o;
    o.x = f2bf(v.x); o.y = f2bf(v.y); o.z = f2bf(v.z); o.w = f2bf(v.w);
    ((ushort4*)Xb)[i] = o;
    return;
  }
  const float* in; u16* out; int R, C, bx, by;
  if (b < CAST_BLKS + TQ_BLKS) {
    int bb = b - CAST_BLKS; bx = bb % TQ_BX; by = bb / TQ_BX;
    in = w_qkv; out = Wqt; R = HIDDEN; C = QKV_N;
  } else {
    int bb = b - CAST_BLKS - TQ_BLKS; bx = bb % TO_BX; by = bb / TO_BX;
    in = w_o; out = Wot; R = QSIZE; C = HIDDEN;
  }
  const int r0 = by * 64, c0 = bx * 32;
  const int tx = tid & 31, ty = tid >> 5;
#pragma unroll
  for (int i = 0; i < 64; i += 8)
    tile[tx][ty + i] = in[(size_t)(r0 + ty + i) * C + c0 + tx];
  __syncthreads();
  const int tx2 = tid & 63, ty2 = tid >> 6;
#pragma unroll
  for (int i = 0; i < 32; i += 4)
    out[(size_t)(c0 + ty2 + i) * R + r0 + tx2] = f2bf(tile[ty2 + i][tx2]);
}

// ---------------- bf16 MFMA GEMM, 128x128 tile, BK=64, XOR-swizzled LDS ----------------
// MODE 0: f32 store to Cout (col-clamped). MODE 1: fused rope epilogue ->
// q/k roped into qb/kb, v raw into vb (tile = exactly 2 heads; x2 partner is
// acc[i][j+2] in the same lane).
template <int MODE>
__global__ __launch_bounds__(256)
void gemm_bt_kernel(const u16* __restrict__ A, const u16* __restrict__ B,
                    float* __restrict__ Cout, const int* __restrict__ positions,
                    u16* __restrict__ qb, u16* __restrict__ kb,
                    u16* __restrict__ vb, int K, int Bvalid, int Nout, int ldc) {
  __shared__ __align__(16) u16 As[128 * 64];
  __shared__ __align__(16) u16 Bs[128 * 64];
  const int tid = threadIdx.x;
  const int lane = tid & 63, wave = tid >> 6;
  const int quad = lane >> 4, l16 = lane & 15;
  const int wm = wave >> 1, wn = wave & 1;
  const int m0 = blockIdx.x * 128, n0 = blockIdx.y * 128;

  const u16* Aptr[4]; const u16* Bptr[4]; u16* Alds[4]; u16* Blds[4];
#pragma unroll
  for (int it = 0; it < 4; ++it) {
    int c = it * 256 + tid;
    int r = c >> 3;
    int lcol = ((c & 7) ^ (r & 7)) * 8;           // XOR swizzle on GLOBAL side
    Aptr[it] = A + (size_t)(m0 + r) * K + lcol;
    int br = n0 + r; br = br < Bvalid ? br : Bvalid - 1;
    Bptr[it] = B + (size_t)br * K + lcol;
    Alds[it] = As + c * 8;
    Blds[it] = Bs + c * 8;
  }

  f32x4 acc[4][4] = {};
  const int sw0 = (quad ^ (l16 & 7)) * 8;         // swizzled chunk offset, kk=0

  for (int kt = 0; kt < K; kt += 64) {
#pragma unroll
    for (int it = 0; it < 4; ++it) gload16(Aptr[it] + kt, Alds[it]);
#pragma unroll
    for (int it = 0; it < 4; ++it) gload16(Bptr[it] + kt, Blds[it]);
    asm volatile("s_waitcnt vmcnt(0)" ::: "memory");
    __syncthreads();
#pragma unroll
    for (int kk = 0; kk < 2; ++kk) {
      const int swo = sw0 ^ (kk * 32);
      short8 af[4], bf[4];
#pragma unroll
      for (int i = 0; i < 4; ++i)
        af[i] = *(const short8*)(As + (wm * 64 + i * 16 + l16) * 64 + swo);
#pragma unroll
      for (int j = 0; j < 4; ++j)
        bf[j] = *(const short8*)(Bs + (wn * 64 + j * 16 + l16) * 64 + swo);
#pragma unroll
      for (int i = 0; i < 4; ++i)
#pragma unroll
        for (int j = 0; j < 4; ++j)
          acc[i][j] = __builtin_amdgcn_mfma_f32_16x16x32_bf16(af[i], bf[j], acc[i][j], 0, 0, 0);
    }
    __syncthreads();
  }

  if (MODE == 0) {
#pragma unroll
    for (int i = 0; i < 4; ++i) {
      const int row = m0 + wm * 64 + i * 16 + quad * 4;
#pragma unroll
      for (int j = 0; j < 4; ++j) {
        const int col = n0 + wn * 64 + j * 16 + l16;
        if (col < Nout)
#pragma unroll
          for (int r = 0; r < 4; ++r)
            Cout[(size_t)(row + r) * ldc + col] = acc[i][j][r];
      }
    }
  } else {
    const int region = (n0 < QSIZE) ? 0 : (n0 < QSIZE + KVSIZE ? 1 : 2);
    if (region <= 1) {
      float invs[2];
#pragma unroll
      for (int j = 0; j < 2; ++j)
        invs[j] = exp2f(-(float)(j * 16 + l16) * ROPE_L2);
#pragma unroll
      for (int i = 0; i < 4; ++i) {
#pragma unroll
        for (int r = 0; r < 4; ++r) {
          const int row = m0 + wm * 64 + i * 16 + quad * 4 + r;
          const float pos = (float)positions[row];
#pragma unroll
          for (int j = 0; j < 2; ++j) {
            float s, c;
            sincosf(pos * invs[j], &s, &c);
            const float x1 = acc[i][j][r], x2 = acc[i][j + 2][r];
            const float o1 = x1 * c - x2 * s, o2 = x2 * c + x1 * s;
            const int col = n0 + wn * 64 + j * 16 + l16;
            if (region == 0) {
              qb[(size_t)row * QSIZE + col] = f2bf(o1);
              qb[(size_t)row * QSIZE + col + 32] = f2bf(o2);
            } else {
              kb[(size_t)row * KVSIZE + col - QSIZE] = f2bf(o1);
              kb[(size_t)row * KVSIZE + col - QSIZE + 32] = f2bf(o2);
            }
          }
        }
      }
    } else {
#pragma unroll
      for (int i = 0; i < 4; ++i) {
        const int row = m0 + wm * 64 + i * 16 + quad * 4;
#pragma unroll
        for (int j = 0; j < 4; ++j) {
          const int col = n0 + wn * 64 + j * 16 + l16 - (QSIZE + KVSIZE);
#pragma unroll
          for (int r = 0; r < 4; ++r)
            vb[(size_t)(row + r) * KVSIZE + col] = f2bf(acc[i][j][r]);
        }
      }
    }
  }
}

// ---------------- windowed attention with sinks ----------------
// block = (32-query tile, kv-group): grid 64x8 = 512 blocks = 2/CU.
// Keys [q0-128, q0+32) = 160. After staging (K->LDS->regs, V->LDS transposed),
// the 4 waves run 100% barrier-free: wave w = (strip w&1, heads {w>>1}+{0,2,4,6}),
// each with a private P region. All LDS strides conflict-free (72 / 164).
__global__ __launch_bounds__(256, 2)
void attn_kernel(const u16* __restrict__ qb, const u16* __restrict__ kb,
                 const u16* __restrict__ vb, const float* __restrict__ sinks,
                 u16* __restrict__ attnb) {
  __shared__ __align__(16) u16 Ks[160 * 72];      // 23040 B
  __shared__ __align__(16) u16 Vt[64 * 164];      // 20992 B, V^T [dim][key]
  __shared__ __align__(16) u16 Pb[4 * 16 * 164];  // 20992 B, per-wave P (Vraw first)
  const int qt = blockIdx.x, g = blockIdx.y;
  const int q0 = qt * 32, kstart = q0 - 128;
  const int tid = threadIdx.x;
  const int lane = tid & 63, wave = tid >> 6;
  const int quad = lane >> 4, l16 = lane & 15;

  // stage K 160x64 -> Ks (stride 72)
  for (int s = tid; s < 1280; s += 256) {
    int r = s >> 3, c8 = (s & 7) * 8;
    int tg = kstart + r; tg = tg < 0 ? 0 : tg;
    *(short8*)(Ks + r * 72 + c8) =
        *(const short8*)(kb + (size_t)tg * KVSIZE + g * HD + c8);
  }
  // stage V raw 160x64 into Pb via global_load_lds (lane-contiguous)
  {
    const u16* vbase = vb + g * HD;
#pragma unroll
    for (int it = 0; it < 5; ++it) {
      int s = it * 256 + tid;
      int r = s >> 3, c8 = (s & 7) * 8;
      int tg = kstart + r; tg = tg < 0 ? 0 : tg;
      gload16(vbase + (size_t)tg * KVSIZE + c8, Pb + s * 8);
    }
  }
  asm volatile("s_waitcnt vmcnt(0)" ::: "memory");
  __syncthreads();

  // K fragments -> registers (Ks persists; no barrier needed after)
  short8 bk[10][2];
#pragma unroll
  for (int jf = 0; jf < 10; ++jf)
#pragma unroll
    for (int kk = 0; kk < 2; ++kk)
      bk[jf][kk] = *(const short8*)(Ks + (jf * 16 + l16) * 72 + kk * 32 + quad * 8);

  // transpose Vraw[key][dim] (in Pb) -> Vt[dim][key] (stride 164)
  for (int s = tid; s < 1280; s += 256) {
    int k8 = s >> 6, d = s & 63;
    short8 tmp;
#pragma unroll
    for (int j = 0; j < 8; ++j) tmp[j] = (short)Pb[(k8 * 8 + j) * 64 + d];
    *(short8*)(Vt + d * 164 + k8 * 8) = tmp;
  }
  __syncthreads();

  // barrier-free head loop
  const int strip = wave & 1, hb = wave >> 1;
  const int qrow0 = q0 + strip * 16;
  u16* Pw = Pb + wave * 16 * 164;
  for (int hh = 0; hh < 4; ++hh) {
    const int h = g * 8 + hb + hh * 2;
    short8 aq[2];
#pragma unroll
    for (int kk = 0; kk < 2; ++kk)
      aq[kk] = *(const short8*)(qb + (size_t)(qrow0 + l16) * QSIZE + h * HD + kk * 32 + quad * 8);
    f32x4 sc[10];
#pragma unroll
    for (int jf = 0; jf < 10; ++jf) {
      f32x4 c = {0.f, 0.f, 0.f, 0.f};
#pragma unroll
      for (int kk = 0; kk < 2; ++kk)
        c = __builtin_amdgcn_mfma_f32_16x16x32_bf16(aq[kk], bk[jf][kk], c, 0, 0, 0);
      sc[jf] = c;
    }

    const float sink = sinks[h];
    float pinv[4];
#pragma unroll
    for (int r = 0; r < 4; ++r) {
      const int qg = qrow0 + quad * 4 + r;
      float mx = -3.0e38f;
#pragma unroll
      for (int jf = 0; jf < 10; ++jf) {
        int kg = kstart + jf * 16 + l16;
        bool valid = (kg >= 0) && (kg <= qg) && (qg - kg < WINDOW);
        float sv = valid ? sc[jf][r] * SCALE_F : -3.0e38f;
        sc[jf][r] = sv;
        mx = fmaxf(mx, sv);
      }
#pragma unroll
      for (int d = 1; d < 16; d <<= 1) mx = fmaxf(mx, __shfl_xor(mx, d, 64));
      mx = fmaxf(mx, sink);
      float sum = 0.f;
#pragma unroll
      for (int jf = 0; jf < 10; ++jf) {
        float e = __expf(sc[jf][r] - mx);
        sc[jf][r] = e;
        sum += e;
      }
#pragma unroll
      for (int d = 1; d < 16; d <<= 1) sum += __shfl_xor(sum, d, 64);
      sum += __expf(sink - mx);
      pinv[r] = 1.0f / sum;
    }

#pragma unroll
    for (int jf = 0; jf < 10; ++jf)
#pragma unroll
      for (int r = 0; r < 4; ++r)
        Pw[(quad * 4 + r) * 164 + jf * 16 + l16] = f2bf(sc[jf][r] * pinv[r]);

    f32x4 o[4] = {};
#pragma unroll
    for (int kk = 0; kk < 5; ++kk) {
      short8 ap = *(const short8*)(Pw + l16 * 164 + kk * 32 + quad * 8);
#pragma unroll
      for (int jf = 0; jf < 4; ++jf) {
        short8 bv = *(const short8*)(Vt + (jf * 16 + l16) * 164 + kk * 32 + quad * 8);
        o[jf] = __builtin_amdgcn_mfma_f32_16x16x32_bf16(ap, bv, o[jf], 0, 0, 0);
      }
    }
#pragma unroll
    for (int jf = 0; jf < 4; ++jf)
#pragma unroll
      for (int r = 0; r < 4; ++r) {
        int qg = qrow0 + quad * 4 + r;
        attnb[(size_t)qg * QSIZE + h * HD + jf * 16 + l16] = f2bf(o[jf][r]);
      }
  }
}

extern "C" void kernel_launch(void* const* d_in, const int* in_sizes, int n_in,
                              void* d_out, int out_size, void* d_ws, size_t ws_size,
                              hipStream_t stream) {
  (void)in_sizes; (void)n_in; (void)out_size; (void)ws_size;
  const int*   positions = (const int*)d_in[0];
  const float* hidden    = (const float*)d_in[1];
  const float* w_qkv     = (const float*)d_in[2];
  const float* w_o       = (const float*)d_in[3];
  const float* sinks     = (const float*)d_in[4];

  char* p = (char*)d_ws;
  u16* Xb    = (u16*)p; p += (size_t)T_SEQ * HIDDEN * 2;   // hidden bf16
  u16* Wqt   = (u16*)p; p += (size_t)QKV_N * HIDDEN * 2;   // w_qkv^T bf16 [5120][2880]
  u16* Wot   = (u16*)p; p += (size_t)HIDDEN * QSIZE * 2;   // w_o^T bf16 [2880][4096]
  u16* qb    = (u16*)p; p += (size_t)T_SEQ * QSIZE * 2;    // roped q bf16
  u16* kb    = (u16*)p; p += (size_t)T_SEQ * KVSIZE * 2;   // roped k bf16
  u16* vb    = (u16*)p; p += (size_t)T_SEQ * KVSIZE * 2;   // v bf16
  u16* attnb = (u16*)p; p += (size_t)T_SEQ * QSIZE * 2;    // attention out bf16

  prep_kernel<<<PREP_BLKS, 256, 0, stream>>>(hidden, w_qkv, w_o, Xb, Wqt, Wot);
  gemm_bt_kernel<1><<<dim3(T_SEQ / 128, QKV_N / 128), 256, 0, stream>>>(
      Xb, Wqt, nullptr, positions, qb, kb, vb, HIDDEN, QKV_N, QKV_N, QKV_N);
  attn_kernel<<<dim3(T_SEQ / 32, NKV), 256, 0, stream>>>(qb, kb, vb, sinks, attnb);
  gemm_bt_kernel<0><<<dim3(T_SEQ / 128, 23), 256, 0, stream>>>(
      attnb, Wot, (float*)d_out, nullptr, nullptr, nullptr, nullptr,
      QSIZE, HIDDEN, HIDDEN, HIDDEN);
}